// Round 6
// baseline (265.326 us; speedup 1.0000x reference)
//
#include <hip/hip_runtime.h>
#include <hip/hip_bf16.h>

// Shapes: B=8, Q=1, T=2048, H=512, V=32000
#define Hdim 512
#define Bdim 8
#define Tdim 2048
#define Vdim 32000
#define OUTW (Vdim + Tdim)        // 34048
#define DEC_TILES (Vdim / 128)    // 250
#define REP_TILES ((Bdim * Tdim) / 128)  // 128
#define NTILES (DEC_TILES + REP_TILES)   // 378
#define PROWS (Vdim + Bdim * Tdim)       // 48384

typedef __attribute__((ext_vector_type(8))) short short8;
typedef __attribute__((ext_vector_type(16))) float f32x16;

__device__ __forceinline__ unsigned bfr(float f) {
    union { float f; unsigned u; } x; x.f = f;
    return (x.u + 0x7FFFu + ((x.u >> 16) & 1u)) >> 16;
}
__device__ __forceinline__ unsigned packbf2(float a, float b) {
    __hip_bfloat162 h = __float22bfloat162_rn(make_float2(a, b));  // a -> low 16
    union { __hip_bfloat162 h; unsigned u; } c; c.h = h;
    return c.u;
}
__device__ __forceinline__ float lo16f(unsigned u) { return __uint_as_float(u << 16); }
__device__ __forceinline__ float hi16f(unsigned u) { return __uint_as_float(u & 0xffff0000u); }

// ---------------- prep: w1t -> bf16 [n][k] + qp, one tiny launch ----------------
#define WT_BLOCKS 128                  // 512x512 elems, 8 per thread
#define QP_BLOCKS (Bdim * Hdim / 4)    // 1024 blocks of 4 waves

__global__ __launch_bounds__(256) void prep_kernel(
    const float* __restrict__ w1, const float* __restrict__ x,
    const float* __restrict__ b1,
    unsigned short* __restrict__ wt, float* __restrict__ qp)
{
    const int bid = blockIdx.x;
    if (bid < WT_BLOCKS) {
        // wt[n][kk] = bf16(w1[n*1024 + 512 + kk])
        const int i = bid * 256 + threadIdx.x;   // 8-elem group index
        const int n = i >> 6;
        const int kk = (i & 63) * 8;
        const float4* s = (const float4*)(w1 + (size_t)n * 1024 + 512 + kk);
        const float4 v0 = s[0], v1 = s[1];
        uint4 o;
        o.x = packbf2(v0.x, v0.y); o.y = packbf2(v0.z, v0.w);
        o.z = packbf2(v1.x, v1.y); o.w = packbf2(v1.z, v1.w);
        ((uint4*)wt)[i] = o;
    } else {
        // qp[b,k] = x[b,:].w1q[k,:] + b1[k], one wave per (b,k)
        const int widx = (bid - WT_BLOCKS) * 4 + (threadIdx.x >> 6);
        const int lane = threadIdx.x & 63;
        const int b = widx >> 9, k = widx & 511;
        const float4* xr = (const float4*)(x + b * Hdim);
        const float4* wr = (const float4*)(w1 + (size_t)k * 1024);
        float4 x0 = xr[lane * 2], x1 = xr[lane * 2 + 1];
        float4 w0 = wr[lane * 2], w1v = wr[lane * 2 + 1];
        float s = x0.x * w0.x + x0.y * w0.y + x0.z * w0.z + x0.w * w0.w
                + x1.x * w1v.x + x1.y * w1v.y + x1.z * w1v.z + x1.w * w1v.w;
#pragma unroll
        for (int off = 32; off > 0; off >>= 1) s += __shfl_down(s, off);
        if (lane == 0) qp[b * Hdim + k] = s + b1[k];
    }
}

// ---------------- MFMA GEMM, fp32 A read directly (in-kernel cvt) ----------------
// Grid 1536 (48 groups x 32): mt = (b>>5)*8 + (b&7), chunk = (b>>3)&3 so the 4
// chunk-partners of one mt share blockIdx%8 (same XCD -> shared L2 A-tile).
__global__ __launch_bounds__(256, 2) void gemm_kernel(
    const float* __restrict__ Adec,            // 32000 x 512 fp32 (original)
    const float* __restrict__ Atgt,            // 16384 x 512 fp32 (original)
    const unsigned short* __restrict__ Wt,     // 512 x 512 bf16 (w1t [n][k])
    unsigned short* __restrict__ P)            // 48384 x 512 bf16
{
    __shared__ struct { unsigned short A[128][64]; unsigned short W[128][64]; } u;

    const int tid  = threadIdx.x;
    const int lane = tid & 63;
    const int w    = tid >> 6;

    const int b = blockIdx.x;
    const int mt = (b >> 5) * 8 + (b & 7);
    if (mt >= NTILES) return;
    const int chunk = (b >> 3) & 3;
    const int n0 = chunk << 7;
    const bool is_dec = (mt < DEC_TILES);
    const int m0 = (is_dec ? mt : mt - DEC_TILES) << 7;
    const float* __restrict__ Af = is_dec ? Adec : Atgt;
    const int base = is_dec ? m0 : Vdim + m0;   // P row base

    // staging thread mapping
    const int art = tid >> 4;   // A row-in-pass (16 rows/pass, 8 passes)
    const int ac4 = tid & 15;   // A k-quad (float4)
    const int wrt = tid >> 3;   // W row-in-pass (32 rows/pass, 4 passes)
    const int wgc = tid & 7;    // W k-group (uint4 = 8 bf16)

    const float4* gA = (const float4*)(Af + (size_t)(m0 + art) * 512) + ac4;
    const uint4*  gW = (const uint4*)(Wt + (size_t)(n0 + wrt) * 512) + wgc;

    f32x16 acc00, acc01, acc10, acc11;
#pragma unroll
    for (int i = 0; i < 16; ++i) { acc00[i] = 0.f; acc01[i] = 0.f; acc10[i] = 0.f; acc11[i] = 0.f; }

    const int wm  = (w & 1) << 6;
    const int wn  = (w >> 1) << 6;
    const int l31 = lane & 31;
    const int kh  = lane >> 5;

    float4 ra[8];
    uint4  rw[4];
    // prefetch h=0   (A row stride 512 f32 = 128 float4; 16 rows = 2048 float4)
#pragma unroll
    for (int p = 0; p < 8; ++p) ra[p] = gA[p * 2048];
#pragma unroll
    for (int p = 0; p < 4; ++p) rw[p] = gW[p * 2048];   // W: 32 rows x 64 uint4

#pragma unroll
    for (int h = 0; h < 8; ++h) {
        __syncthreads();   // prev iter's LDS readers done
        // stage registers -> swizzled bf16 LDS
#pragma unroll
        for (int p = 0; p < 8; ++p) {
            const int r = p * 16 + art;
            const int off = (((ac4 >> 1) ^ (r & 7)) << 3) + ((ac4 & 1) << 2);
            uint2 v;
            v.x = packbf2(ra[p].x, ra[p].y);
            v.y = packbf2(ra[p].z, ra[p].w);
            *(uint2*)&u.A[r][off] = v;
        }
#pragma unroll
        for (int p = 0; p < 4; ++p) {
            const int r = p * 32 + wrt;
            const int off = ((wgc ^ (r & 7)) << 3);
            *(uint4*)&u.W[r][off] = rw[p];
        }
        __syncthreads();
        // prefetch next tile (hides under the MFMA loop below)
        if (h < 7) {
#pragma unroll
            for (int p = 0; p < 8; ++p) ra[p] = gA[p * 2048 + (h + 1) * 16];
            // FIX (round-5 bug): k-tile = 64 bf16 = 8 uint4 per row, not 4.
#pragma unroll
            for (int p = 0; p < 4; ++p) rw[p] = gW[p * 2048 + (h + 1) * 8];
        }
#pragma unroll
        for (int s = 0; s < 4; ++s) {
            const int g  = s * 2 + kh;
            const int ca = ((g ^ (l31 & 7)) << 3);
            short8 a0 = *(const short8*)&u.A[wm + l31][ca];
            short8 a1 = *(const short8*)&u.A[wm + l31 + 32][ca];
            short8 b0 = *(const short8*)&u.W[wn + l31][ca];
            short8 b1 = *(const short8*)&u.W[wn + l31 + 32][ca];
            acc00 = __builtin_amdgcn_mfma_f32_32x32x16_bf16(a0, b0, acc00, 0, 0, 0);
            acc01 = __builtin_amdgcn_mfma_f32_32x32x16_bf16(a0, b1, acc01, 0, 0, 0);
            acc10 = __builtin_amdgcn_mfma_f32_32x32x16_bf16(a1, b0, acc10, 0, 0, 0);
            acc11 = __builtin_amdgcn_mfma_f32_32x32x16_bf16(a1, b1, acc11, 0, 0, 0);
        }
    }

    // C/D layout (verified m74/m101): col=lane&31, row=(r&3)+8*(r>>2)+4*(lane>>5)
#pragma unroll
    for (int r = 0; r < 16; ++r) {
        const int ra2 = (r & 3) + ((r >> 2) << 3) + (kh << 2);   // 0..31
        const size_t r0 = (size_t)(base + wm + ra2) * 512 + n0;
        const size_t r1 = (size_t)(base + wm + 32 + ra2) * 512 + n0;
        P[r0 + wn + l31]      = (unsigned short)bfr(acc00[r]);
        P[r0 + wn + 32 + l31] = (unsigned short)bfr(acc01[r]);
        P[r1 + wn + l31]      = (unsigned short)bfr(acc10[r]);
        P[r1 + wn + 32 + l31] = (unsigned short)bfr(acc11[r]);
    }
}

// ---------------- epilogue: out = reduce_n relu(P + qp) . w2, + mask ----------------
__global__ __launch_bounds__(256) void epi_kernel(
    const unsigned short* __restrict__ P, const float* __restrict__ qp,
    const float* __restrict__ w2, const float* __restrict__ mask,
    float* __restrict__ out)
{
    const int blk = blockIdx.x;
    const int tid = threadIdx.x;
    const int lane = tid & 63;
    const int wv = tid >> 6;
    const int c0 = lane * 8;
    const bool is_dec = (blk < DEC_TILES);

    const float4 w20 = *(const float4*)(w2 + c0);
    const float4 w21 = *(const float4*)(w2 + c0 + 4);

    if (is_dec) {
        const int row0 = blk * 128 + wv * 32;
        float4 q0[8], q1[8];
#pragma unroll
        for (int b = 0; b < 8; ++b) {
            q0[b] = *(const float4*)(qp + b * Hdim + c0);
            q1[b] = *(const float4*)(qp + b * Hdim + c0 + 4);
        }
        for (int i = 0; i < 32; ++i) {
            const uint4 pv = *(const uint4*)(P + (size_t)(row0 + i) * 512 + c0);
            float p[8];
            p[0] = lo16f(pv.x); p[1] = hi16f(pv.x);
            p[2] = lo16f(pv.y); p[3] = hi16f(pv.y);
            p[4] = lo16f(pv.z); p[5] = hi16f(pv.z);
            p[6] = lo16f(pv.w); p[7] = hi16f(pv.w);
            float s[8];
#pragma unroll
            for (int b = 0; b < 8; ++b) {
                float t;
                t  = fmaxf(p[0] + q0[b].x, 0.f) * w20.x;
                t += fmaxf(p[1] + q0[b].y, 0.f) * w20.y;
                t += fmaxf(p[2] + q0[b].z, 0.f) * w20.z;
                t += fmaxf(p[3] + q0[b].w, 0.f) * w20.w;
                t += fmaxf(p[4] + q1[b].x, 0.f) * w21.x;
                t += fmaxf(p[5] + q1[b].y, 0.f) * w21.y;
                t += fmaxf(p[6] + q1[b].z, 0.f) * w21.z;
                t += fmaxf(p[7] + q1[b].w, 0.f) * w21.w;
                s[b] = t;
            }
#pragma unroll
            for (int off = 32; off > 0; off >>= 1)
#pragma unroll
                for (int b = 0; b < 8; ++b) s[b] += __shfl_xor(s[b], off);
            if (lane == 0) {
#pragma unroll
                for (int b = 0; b < 8; ++b)
                    out[(size_t)b * OUTW + row0 + i] = s[b];
            }
        }
    } else {
        const int rl0 = (blk - DEC_TILES) * 128 + wv * 32;
        const int b = rl0 >> 11;
        const float4 q0 = *(const float4*)(qp + b * Hdim + c0);
        const float4 q1 = *(const float4*)(qp + b * Hdim + c0 + 4);
        for (int i = 0; i < 32; ++i) {
            const int rr = rl0 + i;
            const uint4 pv = *(const uint4*)(P + (size_t)(Vdim + rr) * 512 + c0);
            float p[8];
            p[0] = lo16f(pv.x); p[1] = hi16f(pv.x);
            p[2] = lo16f(pv.y); p[3] = hi16f(pv.y);
            p[4] = lo16f(pv.z); p[5] = hi16f(pv.z);
            p[6] = lo16f(pv.w); p[7] = hi16f(pv.w);
            float s;
            s  = fmaxf(p[0] + q0.x, 0.f) * w20.x;
            s += fmaxf(p[1] + q0.y, 0.f) * w20.y;
            s += fmaxf(p[2] + q0.z, 0.f) * w20.z;
            s += fmaxf(p[3] + q0.w, 0.f) * w20.w;
            s += fmaxf(p[4] + q1.x, 0.f) * w21.x;
            s += fmaxf(p[5] + q1.y, 0.f) * w21.y;
            s += fmaxf(p[6] + q1.z, 0.f) * w21.z;
            s += fmaxf(p[7] + q1.w, 0.f) * w21.w;
#pragma unroll
            for (int off = 32; off > 0; off >>= 1) s += __shfl_xor(s, off);
            if (lane == 0) {
                const int t = rr & 2047;
                const float mv = mask[b * Tdim + t];
                out[(size_t)b * OUTW + Vdim + t] = mv * s - 1000.f * (1.f - mv);
            }
        }
    }
}

extern "C" void kernel_launch(void* const* d_in, const int* in_sizes, int n_in,
                              void* d_out, int out_size, void* d_ws, size_t ws_size,
                              hipStream_t stream) {
    const float* input_embeds  = (const float*)d_in[0];  // (8,1,512)
    const float* target_embeds = (const float*)d_in[1];  // (8,2048,512)
    const float* input_mask    = (const float*)d_in[2];  // (8,2048)
    const float* w1            = (const float*)d_in[3];  // (512,1024)
    const float* b1            = (const float*)d_in[4];  // (512,)
    const float* w2            = (const float*)d_in[5];  // (512,)
    const float* decoder_w     = (const float*)d_in[6];  // (32000,512)
    float* out = (float*)d_out;

    // ws: qp 16 KB | P bf16 48384x512 (49.5 MB) | wt bf16 512x512 (512 KB)
    float* qp = (float*)d_ws;
    unsigned short* Pbuf = (unsigned short*)((char*)d_ws + 16384);
    unsigned short* wt   = Pbuf + (size_t)PROWS * Hdim;

    prep_kernel<<<WT_BLOCKS + QP_BLOCKS, 256, 0, stream>>>(w1, input_embeds, b1, wt, qp);
    gemm_kernel<<<48 * 32, 256, 0, stream>>>(decoder_w, target_embeds, wt, Pbuf);
    epi_kernel<<<NTILES, 256, 0, stream>>>(Pbuf, qp, w2, input_mask, out);
}

// Round 7
// 264.734 us; speedup vs baseline: 1.0022x; 1.0022x over previous
//
#include <hip/hip_runtime.h>
#include <hip/hip_bf16.h>

// Shapes: B=8, Q=1, T=2048, H=512, V=32000
#define Hdim 512
#define Bdim 8
#define Tdim 2048
#define Vdim 32000
#define OUTW (Vdim + Tdim)        // 34048
#define DEC_TILES (Vdim / 128)    // 250
#define REP_TILES ((Bdim * Tdim) / 128)  // 128
#define NTILES (DEC_TILES + REP_TILES)   // 378
#define PROWS (Vdim + Bdim * Tdim)       // 48384

typedef __attribute__((ext_vector_type(8))) short short8;
typedef __attribute__((ext_vector_type(16))) float f32x16;

__device__ __forceinline__ unsigned bfr(float f) {
    union { float f; unsigned u; } x; x.f = f;
    return (x.u + 0x7FFFu + ((x.u >> 16) & 1u)) >> 16;
}
__device__ __forceinline__ unsigned packbf2(float a, float b) {
    __hip_bfloat162 h = __float22bfloat162_rn(make_float2(a, b));  // a -> low 16
    union { __hip_bfloat162 h; unsigned u; } c; c.h = h;
    return c.u;
}
__device__ __forceinline__ float lo16f(unsigned u) { return __uint_as_float(u << 16); }
__device__ __forceinline__ float hi16f(unsigned u) { return __uint_as_float(u & 0xffff0000u); }

union U8 { unsigned u[4]; short8 s; };
__device__ __forceinline__ short8 cvt8(const float4 f0, const float4 f1) {
    U8 r;
    r.u[0] = packbf2(f0.x, f0.y); r.u[1] = packbf2(f0.z, f0.w);
    r.u[2] = packbf2(f1.x, f1.y); r.u[3] = packbf2(f1.z, f1.w);
    return r.s;
}

// ---------------- prep: w1t -> bf16 [n][k] + qp, one tiny launch ----------------
#define WT_BLOCKS 128                  // 512x512 elems, 8 per thread
#define QP_BLOCKS (Bdim * Hdim / 4)    // 1024 blocks of 4 waves

__global__ __launch_bounds__(256) void prep_kernel(
    const float* __restrict__ w1, const float* __restrict__ x,
    const float* __restrict__ b1,
    unsigned short* __restrict__ wt, float* __restrict__ qp)
{
    const int bid = blockIdx.x;
    if (bid < WT_BLOCKS) {
        // wt[n][kk] = bf16(w1[n*1024 + 512 + kk])
        const int i = bid * 256 + threadIdx.x;   // 8-elem group index
        const int n = i >> 6;
        const int kk = (i & 63) * 8;
        const float4* s = (const float4*)(w1 + (size_t)n * 1024 + 512 + kk);
        const float4 v0 = s[0], v1 = s[1];
        uint4 o;
        o.x = packbf2(v0.x, v0.y); o.y = packbf2(v0.z, v0.w);
        o.z = packbf2(v1.x, v1.y); o.w = packbf2(v1.z, v1.w);
        ((uint4*)wt)[i] = o;
    } else {
        // qp[b,k] = x[b,:].w1q[k,:] + b1[k], one wave per (b,k)
        const int widx = (bid - WT_BLOCKS) * 4 + (threadIdx.x >> 6);
        const int lane = threadIdx.x & 63;
        const int b = widx >> 9, k = widx & 511;
        const float4* xr = (const float4*)(x + b * Hdim);
        const float4* wr = (const float4*)(w1 + (size_t)k * 1024);
        float4 x0 = xr[lane * 2], x1 = xr[lane * 2 + 1];
        float4 w0 = wr[lane * 2], w1v = wr[lane * 2 + 1];
        float s = x0.x * w0.x + x0.y * w0.y + x0.z * w0.z + x0.w * w0.w
                + x1.x * w1v.x + x1.y * w1v.y + x1.z * w1v.z + x1.w * w1v.w;
#pragma unroll
        for (int off = 32; off > 0; off >>= 1) s += __shfl_down(s, off);
        if (lane == 0) qp[b * Hdim + k] = s + b1[k];
    }
}

// ---------------- MFMA GEMM: fp32 A staged via global_load_lds, cvt at read ----------------
// Grid 1536 (48 groups x 32): mt = (b>>5)*8 + (b&7), chunk = (b>>3)&3 so the 4
// chunk-partners of one mt share blockIdx%8 (same XCD -> shared L2 A-tile).
__global__ __launch_bounds__(256, 3) void gemm_kernel(
    const float* __restrict__ Adec,            // 32000 x 512 fp32 (original)
    const float* __restrict__ Atgt,            // 16384 x 512 fp32 (original)
    const unsigned short* __restrict__ Wt,     // 512 x 512 bf16 (w1t [n][k])
    unsigned short* __restrict__ P)            // 48384 x 512 bf16
{
    // A: fp32 [row][64 floats], 32B-chunk XOR swizzle: phys32 = g ^ (row&7)
    // W: bf16 [row][64], 16B-chunk XOR swizzle: phys16 = g ^ (row&7)
    __shared__ struct { float A[128][64]; unsigned short W[128][64]; } u;

    const int tid  = threadIdx.x;
    const int lane = tid & 63;
    const int w    = tid >> 6;

    const int b = blockIdx.x;
    const int mt = (b >> 5) * 8 + (b & 7);
    if (mt >= NTILES) return;
    const int chunk = (b >> 3) & 3;
    const int n0 = chunk << 7;
    const bool is_dec = (mt < DEC_TILES);
    const int m0 = (is_dec ? mt : mt - DEC_TILES) << 7;
    const float* __restrict__ Af = is_dec ? Adec : Atgt;
    const int base = is_dec ? m0 : Vdim + m0;   // P row base

    // A staging: instr j stages rows j*16 + w*4 + (lane>>4); lane's phys32 slot
    // = (lane&15)>>1, which must hold logical c32 = phys32 ^ (row&7).
    const int arow = w * 4 + (lane >> 4);            // j*16 adds 0 mod 8
    const int ac32 = ((lane & 15) >> 1) ^ (arow & 7);
    const float* gA = Af + (size_t)(m0 + arow) * 512 + ac32 * 8 + (lane & 1) * 4;

    // W staging (round-4 verified): instr j stages rows w*32 + j*8 + (lane>>3);
    // phys16 = lane&7 holds logical sc = (lane&7) ^ (row&7), row&7 = lane>>3.
    const int sr = lane >> 3;
    const int sc = (lane & 7) ^ sr;
    const unsigned short* gW = Wt + (size_t)(n0 + w * 32 + sr) * 512 + sc * 8;

    f32x16 acc00, acc01, acc10, acc11;
#pragma unroll
    for (int i = 0; i < 16; ++i) { acc00[i] = 0.f; acc01[i] = 0.f; acc10[i] = 0.f; acc11[i] = 0.f; }

    const int wm  = (w & 1) << 6;
    const int wn  = (w >> 1) << 6;
    const int l31 = lane & 31;
    const int kh  = lane >> 5;
    const int rx7 = l31 & 7;        // (row&7) for both wm+l31 and wm+l31+32

    for (int h0 = 0; h0 < Hdim; h0 += 64) {
        __syncthreads();   // prev iter's LDS readers done
#pragma unroll
        for (int j = 0; j < 8; ++j)
            __builtin_amdgcn_global_load_lds(
                (const __attribute__((address_space(1))) unsigned int*)(gA + j * 16 * 512),
                (__attribute__((address_space(3))) unsigned int*)(&u.A[j * 16 + w * 4][0]),
                16, 0, 0);
#pragma unroll
        for (int j = 0; j < 4; ++j)
            __builtin_amdgcn_global_load_lds(
                (const __attribute__((address_space(1))) unsigned int*)(gW + j * 8 * 512),
                (__attribute__((address_space(3))) unsigned int*)(&u.W[w * 32 + j * 8][0]),
                16, 0, 0);
        gA += 64; gW += 64;
        __syncthreads();   // drains vmcnt(0): staged tile visible
#pragma unroll
        for (int s = 0; s < 4; ++s) {
            const int g  = s * 2 + kh;                 // k-group 0..7
            const int oa = ((g ^ rx7) << 3);           // A float offset (32B chunks)
            const float4 a0f0 = *(const float4*)&u.A[wm + l31][oa];
            const float4 a0f1 = *(const float4*)&u.A[wm + l31][oa + 4];
            const float4 a1f0 = *(const float4*)&u.A[wm + l31 + 32][oa];
            const float4 a1f1 = *(const float4*)&u.A[wm + l31 + 32][oa + 4];
            const short8 a0 = cvt8(a0f0, a0f1);
            const short8 a1 = cvt8(a1f0, a1f1);
            const int ow = ((g ^ rx7) << 3);           // W elem offset (16B chunks)
            const short8 b0 = *(const short8*)&u.W[wn + l31][ow];
            const short8 b1 = *(const short8*)&u.W[wn + l31 + 32][ow];
            acc00 = __builtin_amdgcn_mfma_f32_32x32x16_bf16(a0, b0, acc00, 0, 0, 0);
            acc01 = __builtin_amdgcn_mfma_f32_32x32x16_bf16(a0, b1, acc01, 0, 0, 0);
            acc10 = __builtin_amdgcn_mfma_f32_32x32x16_bf16(a1, b0, acc10, 0, 0, 0);
            acc11 = __builtin_amdgcn_mfma_f32_32x32x16_bf16(a1, b1, acc11, 0, 0, 0);
        }
    }

    // C/D layout (verified m74/m101): col=lane&31, row=(r&3)+8*(r>>2)+4*(lane>>5)
#pragma unroll
    for (int r = 0; r < 16; ++r) {
        const int ra2 = (r & 3) + ((r >> 2) << 3) + (kh << 2);   // 0..31
        const size_t r0 = (size_t)(base + wm + ra2) * 512 + n0;
        const size_t r1 = (size_t)(base + wm + 32 + ra2) * 512 + n0;
        P[r0 + wn + l31]      = (unsigned short)bfr(acc00[r]);
        P[r0 + wn + 32 + l31] = (unsigned short)bfr(acc01[r]);
        P[r1 + wn + l31]      = (unsigned short)bfr(acc10[r]);
        P[r1 + wn + 32 + l31] = (unsigned short)bfr(acc11[r]);
    }
}

// ---------------- epilogue: out = reduce_n relu(P + qp) . w2, + mask ----------------
__global__ __launch_bounds__(256) void epi_kernel(
    const unsigned short* __restrict__ P, const float* __restrict__ qp,
    const float* __restrict__ w2, const float* __restrict__ mask,
    float* __restrict__ out)
{
    const int blk = blockIdx.x;
    const int tid = threadIdx.x;
    const int lane = tid & 63;
    const int wv = tid >> 6;
    const int c0 = lane * 8;
    const bool is_dec = (blk < DEC_TILES);

    const float4 w20 = *(const float4*)(w2 + c0);
    const float4 w21 = *(const float4*)(w2 + c0 + 4);

    if (is_dec) {
        const int row0 = blk * 128 + wv * 32;
        float4 q0[8], q1[8];
#pragma unroll
        for (int b = 0; b < 8; ++b) {
            q0[b] = *(const float4*)(qp + b * Hdim + c0);
            q1[b] = *(const float4*)(qp + b * Hdim + c0 + 4);
        }
        for (int i = 0; i < 32; ++i) {
            const uint4 pv = *(const uint4*)(P + (size_t)(row0 + i) * 512 + c0);
            float p[8];
            p[0] = lo16f(pv.x); p[1] = hi16f(pv.x);
            p[2] = lo16f(pv.y); p[3] = hi16f(pv.y);
            p[4] = lo16f(pv.z); p[5] = hi16f(pv.z);
            p[6] = lo16f(pv.w); p[7] = hi16f(pv.w);
            float s[8];
#pragma unroll
            for (int b = 0; b < 8; ++b) {
                float t;
                t  = fmaxf(p[0] + q0[b].x, 0.f) * w20.x;
                t += fmaxf(p[1] + q0[b].y, 0.f) * w20.y;
                t += fmaxf(p[2] + q0[b].z, 0.f) * w20.z;
                t += fmaxf(p[3] + q0[b].w, 0.f) * w20.w;
                t += fmaxf(p[4] + q1[b].x, 0.f) * w21.x;
                t += fmaxf(p[5] + q1[b].y, 0.f) * w21.y;
                t += fmaxf(p[6] + q1[b].z, 0.f) * w21.z;
                t += fmaxf(p[7] + q1[b].w, 0.f) * w21.w;
                s[b] = t;
            }
#pragma unroll
            for (int off = 32; off > 0; off >>= 1)
#pragma unroll
                for (int b = 0; b < 8; ++b) s[b] += __shfl_xor(s[b], off);
            if (lane == 0) {
#pragma unroll
                for (int b = 0; b < 8; ++b)
                    out[(size_t)b * OUTW + row0 + i] = s[b];
            }
        }
    } else {
        const int rl0 = (blk - DEC_TILES) * 128 + wv * 32;
        const int b = rl0 >> 11;
        const float4 q0 = *(const float4*)(qp + b * Hdim + c0);
        const float4 q1 = *(const float4*)(qp + b * Hdim + c0 + 4);
        for (int i = 0; i < 32; ++i) {
            const int rr = rl0 + i;
            const uint4 pv = *(const uint4*)(P + (size_t)(Vdim + rr) * 512 + c0);
            float p[8];
            p[0] = lo16f(pv.x); p[1] = hi16f(pv.x);
            p[2] = lo16f(pv.y); p[3] = hi16f(pv.y);
            p[4] = lo16f(pv.z); p[5] = hi16f(pv.z);
            p[6] = lo16f(pv.w); p[7] = hi16f(pv.w);
            float s;
            s  = fmaxf(p[0] + q0.x, 0.f) * w20.x;
            s += fmaxf(p[1] + q0.y, 0.f) * w20.y;
            s += fmaxf(p[2] + q0.z, 0.f) * w20.z;
            s += fmaxf(p[3] + q0.w, 0.f) * w20.w;
            s += fmaxf(p[4] + q1.x, 0.f) * w21.x;
            s += fmaxf(p[5] + q1.y, 0.f) * w21.y;
            s += fmaxf(p[6] + q1.z, 0.f) * w21.z;
            s += fmaxf(p[7] + q1.w, 0.f) * w21.w;
#pragma unroll
            for (int off = 32; off > 0; off >>= 1) s += __shfl_xor(s, off);
            if (lane == 0) {
                const int t = rr & 2047;
                const float mv = mask[b * Tdim + t];
                out[(size_t)b * OUTW + Vdim + t] = mv * s - 1000.f * (1.f - mv);
            }
        }
    }
}

extern "C" void kernel_launch(void* const* d_in, const int* in_sizes, int n_in,
                              void* d_out, int out_size, void* d_ws, size_t ws_size,
                              hipStream_t stream) {
    const float* input_embeds  = (const float*)d_in[0];  // (8,1,512)
    const float* target_embeds = (const float*)d_in[1];  // (8,2048,512)
    const float* input_mask    = (const float*)d_in[2];  // (8,2048)
    const float* w1            = (const float*)d_in[3];  // (512,1024)
    const float* b1            = (const float*)d_in[4];  // (512,)
    const float* w2            = (const float*)d_in[5];  // (512,)
    const float* decoder_w     = (const float*)d_in[6];  // (32000,512)
    float* out = (float*)d_out;

    // ws: qp 16 KB | P bf16 48384x512 (49.5 MB) | wt bf16 512x512 (512 KB)
    float* qp = (float*)d_ws;
    unsigned short* Pbuf = (unsigned short*)((char*)d_ws + 16384);
    unsigned short* wt   = Pbuf + (size_t)PROWS * Hdim;

    prep_kernel<<<WT_BLOCKS + QP_BLOCKS, 256, 0, stream>>>(w1, input_embeds, b1, wt, qp);
    gemm_kernel<<<48 * 32, 256, 0, stream>>>(decoder_w, target_embeds, wt, Pbuf);
    epi_kernel<<<NTILES, 256, 0, stream>>>(Pbuf, qp, w2, input_mask, out);
}

// Round 8
// 213.038 us; speedup vs baseline: 1.2454x; 1.2427x over previous
//
#include <hip/hip_runtime.h>
#include <hip/hip_bf16.h>

// Shapes: B=8, Q=1, T=2048, H=512, V=32000
#define Hdim 512
#define Bdim 8
#define Tdim 2048
#define Vdim 32000
#define OUTW (Vdim + Tdim)        // 34048
#define DEC_TILES (Vdim / 128)    // 250
#define REP_TILES ((Bdim * Tdim) / 128)  // 128
#define NTILES (DEC_TILES + REP_TILES)   // 378
#define PROWS (Vdim + Bdim * Tdim)       // 48384

typedef __attribute__((ext_vector_type(8))) short short8;
typedef __attribute__((ext_vector_type(16))) float f32x16;

__device__ __forceinline__ unsigned bfr(float f) {
    union { float f; unsigned u; } x; x.f = f;
    return (x.u + 0x7FFFu + ((x.u >> 16) & 1u)) >> 16;
}
__device__ __forceinline__ unsigned packbf2(float a, float b) {
    __hip_bfloat162 h = __float22bfloat162_rn(make_float2(a, b));  // a -> low 16
    union { __hip_bfloat162 h; unsigned u; } c; c.h = h;
    return c.u;
}
__device__ __forceinline__ float lo16f(unsigned u) { return __uint_as_float(u << 16); }
__device__ __forceinline__ float hi16f(unsigned u) { return __uint_as_float(u & 0xffff0000u); }

union U8 { unsigned u[4]; short8 s; };
__device__ __forceinline__ short8 cvt8(const float4 f0, const float4 f1) {
    U8 r;
    r.u[0] = packbf2(f0.x, f0.y); r.u[1] = packbf2(f0.z, f0.w);
    r.u[2] = packbf2(f1.x, f1.y); r.u[3] = packbf2(f1.z, f1.w);
    return r.s;
}

// ---------------- prep: w1t -> bf16 [n][k] + qp, one tiny launch ----------------
#define WT_BLOCKS 128                  // 512x512 elems, 8 per thread
#define QP_BLOCKS (Bdim * Hdim / 4)    // 1024 blocks of 4 waves

__global__ __launch_bounds__(256) void prep_kernel(
    const float* __restrict__ w1, const float* __restrict__ x,
    const float* __restrict__ b1,
    unsigned short* __restrict__ wt, float* __restrict__ qp)
{
    const int bid = blockIdx.x;
    if (bid < WT_BLOCKS) {
        // wt[n][kk] = bf16(w1[n*1024 + 512 + kk])
        const int i = bid * 256 + threadIdx.x;   // 8-elem group index
        const int n = i >> 6;
        const int kk = (i & 63) * 8;
        const float4* s = (const float4*)(w1 + (size_t)n * 1024 + 512 + kk);
        const float4 v0 = s[0], v1 = s[1];
        uint4 o;
        o.x = packbf2(v0.x, v0.y); o.y = packbf2(v0.z, v0.w);
        o.z = packbf2(v1.x, v1.y); o.w = packbf2(v1.z, v1.w);
        ((uint4*)wt)[i] = o;
    } else {
        // qp[b,k] = x[b,:].w1q[k,:] + b1[k], one wave per (b,k)
        const int widx = (bid - WT_BLOCKS) * 4 + (threadIdx.x >> 6);
        const int lane = threadIdx.x & 63;
        const int b = widx >> 9, k = widx & 511;
        const float4* xr = (const float4*)(x + b * Hdim);
        const float4* wr = (const float4*)(w1 + (size_t)k * 1024);
        float4 x0 = xr[lane * 2], x1 = xr[lane * 2 + 1];
        float4 w0 = wr[lane * 2], w1v = wr[lane * 2 + 1];
        float s = x0.x * w0.x + x0.y * w0.y + x0.z * w0.z + x0.w * w0.w
                + x1.x * w1v.x + x1.y * w1v.y + x1.z * w1v.z + x1.w * w1v.w;
#pragma unroll
        for (int off = 32; off > 0; off >>= 1) s += __shfl_down(s, off);
        if (lane == 0) qp[b * Hdim + k] = s + b1[k];
    }
}

// ---------------- MFMA GEMM: fp32 A staged via global_load_lds, cvt at read ----------------
// Grid 1536 (48 groups x 32): mt = (b>>5)*8 + (b&7), chunk = (b>>3)&3 so the 4
// chunk-partners of one mt share blockIdx%8 (same XCD -> shared L2 A-tile).
__global__ __launch_bounds__(256, 3) void gemm_kernel(
    const float* __restrict__ Adec,            // 32000 x 512 fp32 (original)
    const float* __restrict__ Atgt,            // 16384 x 512 fp32 (original)
    const unsigned short* __restrict__ Wt,     // 512 x 512 bf16 (w1t [n][k])
    unsigned short* __restrict__ P)            // 48384 x 512 bf16
{
    // A: fp32 [row][64], 16B-chunk XOR swizzle: phys16 = logical16 ^ (row&15)
    //    (row = 256B = 16 chunks; per-instruction reads cover all 16 chunks
    //     per 16-lane phase -> <=2 lanes/bank = conflict-free)
    // W: bf16 [row][64], 16B-chunk XOR swizzle: phys16 = g ^ (row&7)  (row=128B)
    __shared__ struct { float A[128][64]; unsigned short W[128][64]; } u;

    const int tid  = threadIdx.x;
    const int lane = tid & 63;
    const int w    = tid >> 6;

    const int b = blockIdx.x;
    const int mt = (b >> 5) * 8 + (b & 7);
    if (mt >= NTILES) return;
    const int chunk = (b >> 3) & 3;
    const int n0 = chunk << 7;
    const bool is_dec = (mt < DEC_TILES);
    const int m0 = (is_dec ? mt : mt - DEC_TILES) << 7;
    const float* __restrict__ Af = is_dec ? Adec : Atgt;
    const int base = is_dec ? m0 : Vdim + m0;   // P row base

    // A staging: instr j covers rows j*16 + w*4 + (lane>>4); lane's phys16
    // slot = lane&15, which must hold logical chunk (lane&15) ^ (row&15).
    const int arow = w * 4 + (lane >> 4);            // row&15 (j*16 adds 0 mod 16)
    const int achk = (lane & 15) ^ arow;
    const float* gA = Af + (size_t)(m0 + arow) * 512 + achk * 4;

    // W staging (round-4 verified): instr j stages rows w*32 + j*8 + (lane>>3);
    // phys16 = lane&7 holds logical sc = (lane&7) ^ (row&7), row&7 = lane>>3.
    const int sr = lane >> 3;
    const int sc = (lane & 7) ^ sr;
    const unsigned short* gW = Wt + (size_t)(n0 + w * 32 + sr) * 512 + sc * 8;

    f32x16 acc00, acc01, acc10, acc11;
#pragma unroll
    for (int i = 0; i < 16; ++i) { acc00[i] = 0.f; acc01[i] = 0.f; acc10[i] = 0.f; acc11[i] = 0.f; }

    const int wm  = (w & 1) << 6;
    const int wn  = (w >> 1) << 6;
    const int l31 = lane & 31;
    const int kh  = lane >> 5;
    const int rx7  = l31 & 7;       // (row&7)  for W reads
    const int rx15 = l31 & 15;      // (row&15) for A reads (rows wm+l31, +32: same mod 16)

    for (int h0 = 0; h0 < Hdim; h0 += 64) {
        __syncthreads();   // prev iter's LDS readers done
#pragma unroll
        for (int j = 0; j < 8; ++j)
            __builtin_amdgcn_global_load_lds(
                (const __attribute__((address_space(1))) unsigned int*)(gA + j * 16 * 512),
                (__attribute__((address_space(3))) unsigned int*)(&u.A[j * 16 + w * 4][0]),
                16, 0, 0);
#pragma unroll
        for (int j = 0; j < 4; ++j)
            __builtin_amdgcn_global_load_lds(
                (const __attribute__((address_space(1))) unsigned int*)(gW + j * 8 * 512),
                (__attribute__((address_space(3))) unsigned int*)(&u.W[w * 32 + j * 8][0]),
                16, 0, 0);
        gA += 64; gW += 64;
        __syncthreads();   // staged tile visible
#pragma unroll
        for (int s = 0; s < 4; ++s) {
            const int g  = s * 2 + kh;                 // k-group 0..7
            // A: logical 16B chunks 2g (k=8g..8g+3) and 2g+1 (k=8g+4..8g+7)
            const int p0 = ((2 * g) ^ rx15) << 2;      // float offset
            const int p1 = ((2 * g + 1) ^ rx15) << 2;
            const float4 a0f0 = *(const float4*)&u.A[wm + l31][p0];
            const float4 a0f1 = *(const float4*)&u.A[wm + l31][p1];
            const float4 a1f0 = *(const float4*)&u.A[wm + l31 + 32][p0];
            const float4 a1f1 = *(const float4*)&u.A[wm + l31 + 32][p1];
            const short8 a0 = cvt8(a0f0, a0f1);
            const short8 a1 = cvt8(a1f0, a1f1);
            const int ow = ((g ^ rx7) << 3);           // W elem offset
            const short8 b0 = *(const short8*)&u.W[wn + l31][ow];
            const short8 b1 = *(const short8*)&u.W[wn + l31 + 32][ow];
            acc00 = __builtin_amdgcn_mfma_f32_32x32x16_bf16(a0, b0, acc00, 0, 0, 0);
            acc01 = __builtin_amdgcn_mfma_f32_32x32x16_bf16(a0, b1, acc01, 0, 0, 0);
            acc10 = __builtin_amdgcn_mfma_f32_32x32x16_bf16(a1, b0, acc10, 0, 0, 0);
            acc11 = __builtin_amdgcn_mfma_f32_32x32x16_bf16(a1, b1, acc11, 0, 0, 0);
        }
    }

    // C/D layout (verified m74/m101): col=lane&31, row=(r&3)+8*(r>>2)+4*(lane>>5)
#pragma unroll
    for (int r = 0; r < 16; ++r) {
        const int ra2 = (r & 3) + ((r >> 2) << 3) + (kh << 2);   // 0..31
        const size_t r0 = (size_t)(base + wm + ra2) * 512 + n0;
        const size_t r1 = (size_t)(base + wm + 32 + ra2) * 512 + n0;
        P[r0 + wn + l31]      = (unsigned short)bfr(acc00[r]);
        P[r0 + wn + 32 + l31] = (unsigned short)bfr(acc01[r]);
        P[r1 + wn + l31]      = (unsigned short)bfr(acc10[r]);
        P[r1 + wn + 32 + l31] = (unsigned short)bfr(acc11[r]);
    }
}

// ---------------- epilogue: out = reduce_n relu(P + qp) . w2, + mask ----------------
// 1512 blocks x 256 thr; block = 32 rows (wave = 8 rows), lane owns 8 n-cols.
#define EPI_DEC_BLOCKS (Vdim / 32)            // 1000
#define EPI_REP_BLOCKS (Bdim * Tdim / 32)     // 512

__global__ __launch_bounds__(256) void epi_kernel(
    const unsigned short* __restrict__ P, const float* __restrict__ qp,
    const float* __restrict__ w2, const float* __restrict__ mask,
    float* __restrict__ out)
{
    const int blk = blockIdx.x;
    const int lane = threadIdx.x & 63;
    const int wv = threadIdx.x >> 6;
    const int c0 = lane * 8;

    const float4 w20 = *(const float4*)(w2 + c0);
    const float4 w21 = *(const float4*)(w2 + c0 + 4);

    if (blk < EPI_DEC_BLOCKS) {
        const int row0 = blk * 32 + wv * 8;
        float4 q0[8], q1[8];
#pragma unroll
        for (int b = 0; b < 8; ++b) {
            q0[b] = *(const float4*)(qp + b * Hdim + c0);
            q1[b] = *(const float4*)(qp + b * Hdim + c0 + 4);
        }
#pragma unroll
        for (int i = 0; i < 8; ++i) {
            const int row = row0 + i;
            const uint4 pv = *(const uint4*)(P + (size_t)row * 512 + c0);
            float p[8];
            p[0] = lo16f(pv.x); p[1] = hi16f(pv.x);
            p[2] = lo16f(pv.y); p[3] = hi16f(pv.y);
            p[4] = lo16f(pv.z); p[5] = hi16f(pv.z);
            p[6] = lo16f(pv.w); p[7] = hi16f(pv.w);
            float s[8];
#pragma unroll
            for (int b = 0; b < 8; ++b) {
                float t;
                t  = fmaxf(p[0] + q0[b].x, 0.f) * w20.x;
                t += fmaxf(p[1] + q0[b].y, 0.f) * w20.y;
                t += fmaxf(p[2] + q0[b].z, 0.f) * w20.z;
                t += fmaxf(p[3] + q0[b].w, 0.f) * w20.w;
                t += fmaxf(p[4] + q1[b].x, 0.f) * w21.x;
                t += fmaxf(p[5] + q1[b].y, 0.f) * w21.y;
                t += fmaxf(p[6] + q1[b].z, 0.f) * w21.z;
                t += fmaxf(p[7] + q1[b].w, 0.f) * w21.w;
                s[b] = t;
            }
            // 3-level butterfly on all 8 batch-sums (within 8-lane groups)
#pragma unroll
            for (int off = 1; off <= 4; off <<= 1)
#pragma unroll
                for (int b = 0; b < 8; ++b) s[b] += __shfl_xor(s[b], off);
            // lane picks its batch (lane&7), 3-level cross-group reduce
            float v = s[lane & 7];
#pragma unroll
            for (int off = 8; off <= 32; off <<= 1) v += __shfl_xor(v, off);
            if (lane < 8) out[(size_t)lane * OUTW + row] = v;
        }
    } else {
        const int rr0 = (blk - EPI_DEC_BLOCKS) * 32 + wv * 8;
        const int b = rr0 >> 11;   // 32-row block never crosses a batch
        const float4 q0 = *(const float4*)(qp + b * Hdim + c0);
        const float4 q1 = *(const float4*)(qp + b * Hdim + c0 + 4);
#pragma unroll
        for (int i = 0; i < 8; ++i) {
            const int rr = rr0 + i;
            const uint4 pv = *(const uint4*)(P + (size_t)(Vdim + rr) * 512 + c0);
            float p[8];
            p[0] = lo16f(pv.x); p[1] = hi16f(pv.x);
            p[2] = lo16f(pv.y); p[3] = hi16f(pv.y);
            p[4] = lo16f(pv.z); p[5] = hi16f(pv.z);
            p[6] = lo16f(pv.w); p[7] = hi16f(pv.w);
            float s;
            s  = fmaxf(p[0] + q0.x, 0.f) * w20.x;
            s += fmaxf(p[1] + q0.y, 0.f) * w20.y;
            s += fmaxf(p[2] + q0.z, 0.f) * w20.z;
            s += fmaxf(p[3] + q0.w, 0.f) * w20.w;
            s += fmaxf(p[4] + q1.x, 0.f) * w21.x;
            s += fmaxf(p[5] + q1.y, 0.f) * w21.y;
            s += fmaxf(p[6] + q1.z, 0.f) * w21.z;
            s += fmaxf(p[7] + q1.w, 0.f) * w21.w;
#pragma unroll
            for (int off = 32; off > 0; off >>= 1) s += __shfl_xor(s, off);
            if (lane == 0) {
                const int t = rr & 2047;
                const float mv = mask[b * Tdim + t];
                out[(size_t)b * OUTW + Vdim + t] = mv * s - 1000.f * (1.f - mv);
            }
        }
    }
}

extern "C" void kernel_launch(void* const* d_in, const int* in_sizes, int n_in,
                              void* d_out, int out_size, void* d_ws, size_t ws_size,
                              hipStream_t stream) {
    const float* input_embeds  = (const float*)d_in[0];  // (8,1,512)
    const float* target_embeds = (const float*)d_in[1];  // (8,2048,512)
    const float* input_mask    = (const float*)d_in[2];  // (8,2048)
    const float* w1            = (const float*)d_in[3];  // (512,1024)
    const float* b1            = (const float*)d_in[4];  // (512,)
    const float* w2            = (const float*)d_in[5];  // (512,)
    const float* decoder_w     = (const float*)d_in[6];  // (32000,512)
    float* out = (float*)d_out;

    // ws: qp 16 KB | P bf16 48384x512 (49.5 MB) | wt bf16 512x512 (512 KB)
    float* qp = (float*)d_ws;
    unsigned short* Pbuf = (unsigned short*)((char*)d_ws + 16384);
    unsigned short* wt   = Pbuf + (size_t)PROWS * Hdim;

    prep_kernel<<<WT_BLOCKS + QP_BLOCKS, 256, 0, stream>>>(w1, input_embeds, b1, wt, qp);
    gemm_kernel<<<48 * 32, 256, 0, stream>>>(decoder_w, target_embeds, wt, Pbuf);
    epi_kernel<<<EPI_DEC_BLOCKS + EPI_REP_BLOCKS, 256, 0, stream>>>(Pbuf, qp, w2, input_mask, out);
}